// Round 1
// 353.851 us; speedup vs baseline: 1.1098x; 1.1098x over previous
//
#include <hip/hip_runtime.h>
#include <math.h>

typedef _Float16 h16;
typedef _Float16 f16x8 __attribute__((ext_vector_type(8)));
typedef float f32x4 __attribute__((ext_vector_type(4)));

#define Bc 4
#define Hc 8
#define Tc 8192
#define Dc 64
#define NCc 64
#define WSZc 128
#define BHc (Bc*Hc)
#define MAXPc 16
#define OVFCAP 4095
#define OUT_ELEMS (16777216u)   // B*H*T*D

#define MFMA16(a,b,c) __builtin_amdgcn_mfma_f32_16x16x32_f16(a,b,c,0,0,0)

// ---------------------------------------------------------------------------
// Kernel 1: dists[bh][c][t] = dot(l2norm(qk[bh][t]), means[h][c])  (fp32)
// plus commitment-loss raw sum atomically added into loss slot aux[1].
// ---------------------------------------------------------------------------
__global__ __launch_bounds__(256) void k_dists(const float* __restrict__ qk,
                                               const float* __restrict__ means,
                                               float* __restrict__ dists,
                                               float* __restrict__ loss_acc) {
    __shared__ float sm[NCc*Dc];       // means[h], 16 KB
    __shared__ float red[4];
    int tid = threadIdx.x;
    int blk = blockIdx.x;              // [0, BH*32)
    int bh  = blk >> 5;                // T/256 = 32 chunks per bh
    int chunk = blk & 31;
    int h = bh & (Hc-1);

    const float* mh = means + (size_t)h*NCc*Dc;
    for (int i = tid; i < NCc*Dc; i += 256) sm[i] = mh[i];
    __syncthreads();

    int t = chunk*256 + tid;
    const float* qrow = qk + ((size_t)bh*Tc + t)*Dc;
    float q[Dc];
    #pragma unroll
    for (int d = 0; d < Dc; d += 4) {
        float4 f = *(const float4*)(qrow + d);
        q[d] = f.x; q[d+1] = f.y; q[d+2] = f.z; q[d+3] = f.w;
    }
    float n2 = 0.f;
    #pragma unroll
    for (int d = 0; d < Dc; d++) n2 += q[d]*q[d];
    float nrm = sqrtf(n2);
    if (nrm < 1e-12f) nrm = 1e-12f;
    float inv = 1.0f/nrm;

    float best = -3.4e38f; int bc = 0;
    float* dbase = dists + ((size_t)bh*NCc)*Tc + (size_t)chunk*256 + tid;
    for (int c = 0; c < NCc; c++) {
        float acc = 0.f;
        const float* mc = sm + c*Dc;
        #pragma unroll
        for (int d = 0; d < Dc; d++) acc += q[d]*mc[d];
        float dv = acc*inv;
        dbase[(size_t)c*Tc] = dv;
        if (dv > best) { best = dv; bc = c; }   // strict > : first max wins
    }
    float ls = 0.f;
    const float* mb = sm + bc*Dc;
    #pragma unroll
    for (int d = 0; d < Dc; d++) {
        float diff = q[d]*inv - mb[d];
        ls += diff*diff;
    }
    float lf = ls;
    #pragma unroll
    for (int o = 32; o >= 1; o >>= 1) lf += __shfl_down(lf, o, 64);
    if ((tid & 63) == 0) red[tid >> 6] = lf;
    __syncthreads();
    if (tid == 0) atomicAdd(loss_acc, red[0]+red[1]+red[2]+red[3]);
}

// ---------------------------------------------------------------------------
// Kernel 2: per (bh,c) exact top-128 of 8192 (ties: lower index), sorted asc,
// with the inverse map (cnt/slots/aux) built in the same kernel.
// Keys live in REGISTERS (32/thread) — LDS is hist+scratch only (~18.4 KB),
// so 4 blocks/CU instead of 3, and no LDS key sweeps.
// ---------------------------------------------------------------------------
__device__ inline unsigned blockScanIncl(unsigned v, volatile unsigned* wsum,
                                         int lane, int wid, unsigned* ptotal) {
    unsigned x = v;
    #pragma unroll
    for (int s = 1; s < 64; s <<= 1) {
        unsigned o = __shfl_up(x, s, 64);
        if (lane >= s) x += o;
    }
    if (lane == 63) wsum[wid] = x;
    __syncthreads();
    unsigned off = 0, tot = 0;
    #pragma unroll
    for (int w2 = 0; w2 < 4; w2++) {
        unsigned s2 = wsum[w2];
        if (w2 < wid) off += s2;
        tot += s2;
    }
    *ptotal = tot;
    return x + off;
}

__global__ __launch_bounds__(256, 4) void k_topk(const float* __restrict__ dists,
                                              int* __restrict__ indices,
                                              unsigned* __restrict__ cnt,
                                              unsigned short* __restrict__ slots,
                                              unsigned* __restrict__ aux) {
    __shared__ unsigned hist[4096];    // 16 KB
    __shared__ unsigned bmap[256];     // 1 KB (8192-bit selection bitmap)
    __shared__ unsigned eqbuf[256];    // 1 KB (tie candidates, rare path)
    __shared__ unsigned wsum[4];
    __shared__ unsigned sh_prefix;
    __shared__ int      sh_k, cnt_eq;

    int tid = threadIdx.x;
    int lane = tid & 63, wid = tid >> 6;
    int bhc = blockIdx.x, bh = bhc >> 6, c = bhc & 63;
    const float* dp = dists + (size_t)bhc*Tc;

    for (int i = tid; i < 4096; i += 256) hist[i] = 0u;
    if (tid == 0) { sh_k = WSZc; sh_prefix = 0u; cnt_eq = 0; }
    bmap[tid] = 0u;
    __syncthreads();

    // load 32 keys/thread into registers (float4-coalesced) + level-0 hist.
    // token for key[ch][j] is  t = ch*1024 + tid*4 + j.
    unsigned key[8][4];
    #pragma unroll
    for (int ch = 0; ch < 8; ch++) {
        float4 f = *(const float4*)(dp + ch*1024 + tid*4);
        float fv[4] = {f.x, f.y, f.z, f.w};
        #pragma unroll
        for (int j = 0; j < 4; j++) {
            unsigned u = __float_as_uint(fv[j]);
            u = (u & 0x80000000u) ? ~u : (u | 0x80000000u);  // order-preserving
            key[ch][j] = u;
            atomicAdd(&hist[u >> 20], 1u);
        }
    }
    __syncthreads();

    unsigned prefix = 0u; int k = WSZc;
    #pragma unroll
    for (int lvl = 0; lvl < 3; lvl++) {
        const int shift   = (lvl == 0) ? 20 : (lvl == 1 ? 8 : 0);
        const int nper    = (lvl == 2) ? 1 : 16;           // bins per thread
        const unsigned nbm = (lvl == 2) ? 255u : 4095u;    // bin mask
        if (lvl > 0) {
            // build filtered histogram for this level (register sweep)
            const unsigned maskH = (lvl == 1) ? 0xFFF00000u : 0xFFFFFF00u;
            for (int i = tid; i <= (int)nbm; i += 256) hist[i] = 0u;
            __syncthreads();
            #pragma unroll
            for (int ch = 0; ch < 8; ch++)
                #pragma unroll
                for (int j = 0; j < 4; j++) {
                    unsigned ky = key[ch][j];
                    if ((ky & maskH) == prefix)
                        atomicAdd(&hist[(ky >> shift) & nbm], 1u);
                }
            __syncthreads();
        }
        // parallel crossing-bin search (suffix = total - excl_ascending)
        int tBase = tid*nper;
        unsigned psum = 0;
        for (int i = 0; i < nper; i++) psum += hist[tBase + i];
        unsigned total;
        unsigned incl = blockScanIncl(psum, wsum, lane, wid, &total);
        unsigned beyond = total - incl;          // keys in bins strictly above
        unsigned suff   = beyond + psum;
        if (beyond < (unsigned)k && (unsigned)k <= suff) {
            unsigned run = beyond;
            for (int i = nper - 1; i >= 0; i--) {
                unsigned hb = hist[tBase + i];
                run += hb;
                if (run >= (unsigned)k) {
                    sh_prefix = prefix | ((unsigned)(tBase + i) << shift);
                    sh_k = k - (int)(run - hb);
                    break;
                }
            }
        }
        __syncthreads();
        prefix = sh_prefix; k = sh_k;
        __syncthreads();
    }
    unsigned Kthr = prefix;    // exact 32-bit threshold key
    int kEq = k;               // # of threshold-equal keys to take (lowest idx)

    // collect: strict-greater -> bitmap; equal -> eqbuf (register sweep)
    #pragma unroll
    for (int ch = 0; ch < 8; ch++)
        #pragma unroll
        for (int j = 0; j < 4; j++) {
            unsigned ky = key[ch][j];
            int t = ch*1024 + tid*4 + j;
            if (ky > Kthr) atomicOr(&bmap[t >> 5], 1u << (t & 31));
            else if (ky == Kthr) {
                int p = atomicAdd(&cnt_eq, 1);
                if (p < 256) eqbuf[p] = (unsigned)t;
            }
        }
    __syncthreads();
    if (cnt_eq == kEq) {       // common path: every equal key is selected
        if (tid < kEq) {
            unsigned t = eqbuf[tid];
            atomicOr(&bmap[t >> 5], 1u << (t & 31));
        }
    } else {                   // rare: sort ties, take lowest kEq indices
        int ce = cnt_eq < 256 ? cnt_eq : 256;
        if (tid >= ce) eqbuf[tid] = 0xFFFFFFFFu;
        __syncthreads();
        for (int k2 = 2; k2 <= 256; k2 <<= 1) {
            for (int j = k2 >> 1; j >= 1; j >>= 1) {
                int i = tid, ixj = i ^ j;
                if (ixj > i) {
                    bool up = ((i & k2) == 0);
                    unsigned a = eqbuf[i], b = eqbuf[ixj];
                    if ((a > b) == up) { eqbuf[i] = b; eqbuf[ixj] = a; }
                }
                __syncthreads();
            }
        }
        if (tid < kEq) {
            unsigned t = eqbuf[tid];
            atomicOr(&bmap[t >> 5], 1u << (t & 31));
        }
    }
    __syncthreads();

    // rank via popcount prefix: indices come out sorted ascending by token
    unsigned w = bmap[tid];
    int pc = __popc(w);
    unsigned total2;
    unsigned incl2 = blockScanIncl((unsigned)pc, wsum, lane, wid, &total2);
    int pos = (int)(incl2 - pc);     // exclusive prefix = output position
    while (w) {
        int b = __ffs(w) - 1; w &= w - 1;
        int t = tid*32 + b;
        indices[(size_t)bhc*WSZc + pos] = t;
        // fused inverse map
        unsigned row = ((unsigned)bh << 13) + (unsigned)t;
        unsigned p2 = atomicAdd(&cnt[row], 1u);
        if (p2 < MAXPc) slots[(size_t)row*MAXPc + p2] = (unsigned short)(c*128 + pos);
        else {
            unsigned o = atomicAdd(&aux[0], 1u);
            if (o < OVFCAP) aux[2+o] = (unsigned)(bhc*WSZc + pos);
        }
        pos++;
    }
}

// ---------------------------------------------------------------------------
// Kernel 3: per (bh,c) fused attention via f16 MFMA (16x16x32).
// Wave w owns rows [32w, 32w+32). shift(rel)[i][j] = rel[i][127+j-i], j<=i.
// ---------------------------------------------------------------------------
__global__ __launch_bounds__(256, 2) void k_attn(const float* __restrict__ qk,
                                                 const float* __restrict__ v,
                                                 const float* __restrict__ relw,
                                                 const int* __restrict__ indices,
                                                 float* __restrict__ bo) {
    __shared__ __align__(16) h16 qf[128*72];      // 18432 B
    __shared__ __align__(16) h16 uv[128*72];      // 18432 B (wf then vt[64][136])
    __shared__ __align__(16) h16 pt[128*136];     // 34816 B
    __shared__ int   sidx[128];
    __shared__ float sinv[128];

    int tid = threadIdx.x;
    int bhc = blockIdx.x, bh = bhc >> 6, h = bh & (Hc-1);
    int lane = tid & 63, wid = tid >> 6;
    int quad = lane >> 4, lj = lane & 15;
    int i0 = wid*32;

    for (int i = tid; i < 128*136/2; i += 256) ((unsigned*)pt)[i] = 0u;
    if (tid < 128) sidx[tid] = indices[(size_t)bhc*WSZc + tid];
    __syncthreads();

    {   // stage q (gathered) + rel_w rows fp32->f16; sinv on the fly
        int i = tid >> 1, hf = tid & 1;
        const float* qrow = qk   + ((size_t)bh*Tc + sidx[i])*Dc + hf*32;
        const float* wrow = relw + ((size_t)i*Hc + h)*Dc + hf*32;
        float n2 = 0.f;
        #pragma unroll
        for (int k8 = 0; k8 < 4; k8++) {
            float4 a = *(const float4*)(qrow + k8*8);
            float4 b = *(const float4*)(qrow + k8*8 + 4);
            float4 c = *(const float4*)(wrow + k8*8);
            float4 d = *(const float4*)(wrow + k8*8 + 4);
            n2 += a.x*a.x + a.y*a.y + a.z*a.z + a.w*a.w
                + b.x*b.x + b.y*b.y + b.z*b.z + b.w*b.w;
            f16x8 hq = {(h16)a.x,(h16)a.y,(h16)a.z,(h16)a.w,
                        (h16)b.x,(h16)b.y,(h16)b.z,(h16)b.w};
            f16x8 hw = {(h16)c.x,(h16)c.y,(h16)c.z,(h16)c.w,
                        (h16)d.x,(h16)d.y,(h16)d.z,(h16)d.w};
            *(f16x8*)&qf[i*72 + hf*32 + k8*8] = hq;
            *(f16x8*)&uv[i*72 + hf*32 + k8*8] = hw;
        }
        n2 += __shfl_xor(n2, 1, 64);
        if (hf == 0) {
            float nr = sqrtf(n2); if (nr < 1e-12f) nr = 1e-12f;
            sinv[i] = 0.125f / nr;
        }
    }
    __syncthreads();

    {   // A1: REL[i][m] = q_i . w_m (K=64); scatter *0.125 into pt[i][m-127+i]
        f32x4 accR[2][8];
        #pragma unroll
        for (int mt = 0; mt < 2; mt++)
            #pragma unroll
            for (int nt = 0; nt < 8; nt++)
                #pragma unroll
                for (int e = 0; e < 4; e++) accR[mt][nt][e] = 0.f;
        #pragma unroll
        for (int k0 = 0; k0 < 64; k0 += 32) {
            f16x8 a0 = *(const f16x8*)&qf[(i0 + lj)*72 + k0 + quad*8];
            f16x8 a1 = *(const f16x8*)&qf[(i0 + 16 + lj)*72 + k0 + quad*8];
            #pragma unroll
            for (int nt = 0; nt < 8; nt++) {
                f16x8 bf = *(const f16x8*)&uv[(nt*16 + lj)*72 + k0 + quad*8];
                accR[0][nt] = MFMA16(a0, bf, accR[0][nt]);
                accR[1][nt] = MFMA16(a1, bf, accR[1][nt]);
            }
        }
        #pragma unroll
        for (int mt = 0; mt < 2; mt++)
            #pragma unroll
            for (int nt = 0; nt < 8; nt++)
                #pragma unroll
                for (int r = 0; r < 4; r++) {
                    int i = i0 + mt*16 + quad*4 + r;
                    int j = nt*16 + lj - 127 + i;
                    if (j >= 0) pt[i*136 + j] = (h16)(accR[mt][nt][r] * 0.125f);
                }
    }

    // prefetch v rows (gathered) into registers
    float4 vr[8];
    {
        int j = tid >> 1, hf = tid & 1;
        const float* vrow = v + ((size_t)bh*Tc + sidx[j])*Dc + hf*32;
        #pragma unroll
        for (int r = 0; r < 8; r++) vr[r] = *(const float4*)(vrow + r*4);
    }
    __syncthreads();   // all waves done reading uv(rel_w) -> region reusable

    f32x4 accS[2][8];
    #pragma unroll
    for (int mt = 0; mt < 2; mt++)
        #pragma unroll
        for (int nt = 0; nt < 8; nt++)
            #pragma unroll
            for (int e = 0; e < 4; e++) accS[mt][nt][e] = 0.f;
    #pragma unroll
    for (int k0 = 0; k0 < 64; k0 += 32) {   // A2: S = Q.Q^T
        f16x8 a0 = *(const f16x8*)&qf[(i0 + lj)*72 + k0 + quad*8];
        f16x8 a1 = *(const f16x8*)&qf[(i0 + 16 + lj)*72 + k0 + quad*8];
        #pragma unroll
        for (int nt = 0; nt < 8; nt++) {
            f16x8 bf = *(const f16x8*)&qf[(nt*16 + lj)*72 + k0 + quad*8];
            accS[0][nt] = MFMA16(a0, bf, accS[0][nt]);
            accS[1][nt] = MFMA16(a1, bf, accS[1][nt]);
        }
    }
    #pragma unroll
    for (int nt = 0; nt < 8; nt++) {   // scale + rel + diag mask
        int j = nt*16 + lj;
        float sj = sinv[j];
        #pragma unroll
        for (int mt = 0; mt < 2; mt++)
            #pragma unroll
            for (int r = 0; r < 4; r++) {
                int i = i0 + mt*16 + quad*4 + r;
                float s = accS[mt][nt][r]*sj + (float)pt[i*136 + j];
                accS[mt][nt][r] = (i == j) ? -50000.0f : s;
            }
    }
    #pragma unroll
    for (int mt = 0; mt < 2; mt++)      // softmax (rows live in 16-lane quads)
        #pragma unroll
        for (int r = 0; r < 4; r++) {
            float mx = accS[mt][0][r];
            #pragma unroll
            for (int nt = 1; nt < 8; nt++) mx = fmaxf(mx, accS[mt][nt][r]);
            #pragma unroll
            for (int st = 1; st <= 8; st <<= 1) mx = fmaxf(mx, __shfl_xor(mx, st, 64));
            float sum = 0.f;
            #pragma unroll
            for (int nt = 0; nt < 8; nt++) {
                float e = __expf(accS[mt][nt][r] - mx);
                accS[mt][nt][r] = e; sum += e;
            }
            #pragma unroll
            for (int st = 1; st <= 8; st <<= 1) sum += __shfl_xor(sum, st, 64);
            float inv = 1.0f/sum;
            #pragma unroll
            for (int nt = 0; nt < 8; nt++) accS[mt][nt][r] *= inv;
        }
    #pragma unroll
    for (int mt = 0; mt < 2; mt++)      // write P (f16) to pt (own rows)
        #pragma unroll
        for (int nt = 0; nt < 8; nt++)
            #pragma unroll
            for (int r = 0; r < 4; r++) {
                int i = i0 + mt*16 + quad*4 + r;
                pt[i*136 + nt*16 + lj] = (h16)accS[mt][nt][r];
            }
    {   // store v^T into uv: vt[d][j], stride 136
        int j = tid >> 1, hf = tid & 1;
        #pragma unroll
        for (int r = 0; r < 8; r++) {
            int d0 = hf*32 + r*4;
            float4 f = vr[r];
            uv[(d0+0)*136 + j] = (h16)f.x;
            uv[(d0+1)*136 + j] = (h16)f.y;
            uv[(d0+2)*136 + j] = (h16)f.z;
            uv[(d0+3)*136 + j] = (h16)f.w;
        }
    }
    __syncthreads();

    f32x4 accO[2][4];
    #pragma unroll
    for (int mt = 0; mt < 2; mt++)
        #pragma unroll
        for (int nt = 0; nt < 4; nt++)
            #pragma unroll
            for (int e = 0; e < 4; e++) accO[mt][nt][e] = 0.f;
    #pragma unroll
    for (int k0 = 0; k0 < 128; k0 += 32) {   // O = P.V (K=128)
        f16x8 a0 = *(const f16x8*)&pt[(i0 + lj)*136 + k0 + quad*8];
        f16x8 a1 = *(const f16x8*)&pt[(i0 + 16 + lj)*136 + k0 + quad*8];
        #pragma unroll
        for (int nt = 0; nt < 4; nt++) {
            f16x8 bf = *(const f16x8*)&uv[(nt*16 + lj)*136 + k0 + quad*8];
            accO[0][nt] = MFMA16(a0, bf, accO[0][nt]);
            accO[1][nt] = MFMA16(a1, bf, accO[1][nt]);
        }
    }
    #pragma unroll
    for (int mt = 0; mt < 2; mt++)
        #pragma unroll
        for (int nt = 0; nt < 4; nt++)
            #pragma unroll
            for (int r = 0; r < 4; r++) {
                int i = i0 + mt*16 + quad*4 + r;
                bo[((size_t)bhc*WSZc + i)*Dc + nt*16 + lj] = accO[mt][nt][r];
            }
}

// ---------------------------------------------------------------------------
// Kernel 4: out[bh,t,:] = (sum of its bo rows + rare ovf) / (cnt+EPS); loss.
// ---------------------------------------------------------------------------
__global__ __launch_bounds__(256) void k_final(const float* __restrict__ bo,
                                               const unsigned short* __restrict__ slots,
                                               const unsigned* __restrict__ cnt,
                                               const int* __restrict__ indices,
                                               const unsigned* __restrict__ aux,
                                               float* __restrict__ out) {
    int row  = blockIdx.x*4 + (threadIdx.x >> 6);   // [0, BH*T)
    int lane = threadIdx.x & 63;
    unsigned c = cnt[row];
    unsigned m = c < MAXPc ? c : MAXPc;
    int bh = row >> 13;
    float acc = 0.f;
    const unsigned short* sl = slots + (size_t)row*MAXPc;
    for (unsigned p = 0; p < m; p++)
        acc += bo[(((size_t)bh << 13) + sl[p])*Dc + lane];
    if (c > MAXPc) {   // astronomically rare
        unsigned n = aux[0]; if (n > OVFCAP) n = OVFCAP;
        int tok = row & 8191;
        for (unsigned q = 0; q < n; q++) {
            unsigned e = aux[2+q];
            if ((int)(e >> 13) == bh && indices[e] == tok)
                acc += bo[(((size_t)bh << 13) + (e & 8191))*Dc + lane];
        }
    }
    out[(size_t)row*Dc + lane] = acc * (1.0f/((float)c + 1e-5f));
    if (row == 0 && lane == 0)
        out[OUT_ELEMS] = ((const float*)aux)[1] * (float)(1e-4 / 16777216.0);
}

extern "C" void kernel_launch(void* const* d_in, const int* in_sizes, int n_in,
                              void* d_out, int out_size, void* d_ws, size_t ws_size,
                              hipStream_t stream) {
    const float* qk    = (const float*)d_in[0];
    const float* v     = (const float*)d_in[1];
    const float* means = (const float*)d_in[2];
    const float* relw  = (const float*)d_in[3];
    float* out = (float*)d_out;
    char*  ws  = (char*)d_ws;

    // workspace layout (bo aliases dists: dists dead after k_topk)
    size_t off = 0;
    float* dists = (float*)(ws + off);
    float* bo    = dists;
    off += (size_t)BHc*NCc*Tc*4;                                           // 64 MB
    int* indices = (int*)(ws + off); off += (size_t)BHc*NCc*WSZc*4;        // 1 MB
    unsigned* cnt = (unsigned*)(ws + off); off += (size_t)BHc*Tc*4;        // 1 MB
    unsigned* aux = (unsigned*)(ws + off); off += (size_t)(2+OVFCAP)*4;    // 16 KB
    unsigned short* slots = (unsigned short*)(ws + off);
    off += (size_t)BHc*Tc*MAXPc*2;                                         // 8 MB

    // single memset covers cnt + aux (adjacent)
    hipMemsetAsync(cnt, 0, (size_t)BHc*Tc*4 + (size_t)(2+OVFCAP)*4, stream);

    k_dists <<<BHc*(Tc/256), 256, 0, stream>>>(qk, means, dists, (float*)aux + 1);
    k_topk  <<<BHc*NCc,      256, 0, stream>>>(dists, indices, cnt, slots, aux);
    k_attn  <<<BHc*NCc,      256, 0, stream>>>(qk, v, relw, indices, bo);
    k_final <<<BHc*Tc/4,     256, 0, stream>>>(bo, slots, cnt, indices, aux, out);
}